// Round 21
// baseline (197.881 us; speedup 1.0000x reference)
//
#include <hip/hip_runtime.h>
#include <hip/hip_bf16.h>

#define BATCH 16
#define SEQ   1024
#define DIM   1024

typedef __attribute__((ext_vector_type(8))) short bf16x8;
typedef __attribute__((ext_vector_type(4))) float f32x4;
typedef __attribute__((ext_vector_type(4))) unsigned short us4;

__device__ __forceinline__ float bfu2f(unsigned short u) {
  union { unsigned int i; float f; } c; c.i = ((unsigned int)u) << 16; return c.f;
}
__device__ __forceinline__ unsigned short f2bfu(float f) {
  union { float f; unsigned int i; } c; c.f = f;
  return (unsigned short)((c.i + 0x7FFFu + ((c.i >> 16) & 1u)) >> 16);
}
__device__ __forceinline__ void async16(void* lds, const void* g) {
  __builtin_amdgcn_global_load_lds(
      (const __attribute__((address_space(1))) unsigned int*)g,
      (__attribute__((address_space(3))) unsigned int*)lds, 16, 0, 0);
}

// ---------------- transpose-cast: out[i,h] = bf16(in[h,i]) for Wq, Wk ----------------
__global__ void castT_kernel(const float* __restrict__ Wq, const float* __restrict__ Wk,
                             unsigned short* __restrict__ WqT,
                             unsigned short* __restrict__ WkT) {
  const float* in = (blockIdx.z == 0) ? Wq : Wk;
  unsigned short* out = (blockIdx.z == 0) ? WqT : WkT;
  __shared__ float t[64][65];
  const int h0 = blockIdx.x * 64, i0 = blockIdx.y * 64;
  const int tid = threadIdx.x;
  const int sub = tid >> 4, c4 = tid & 15;
#pragma unroll
  for (int p = 0; p < 4; ++p) {
    const int row = p * 16 + sub;
    f32x4 v = *(const f32x4*)(in + (size_t)(h0 + row) * DIM + i0 + c4 * 4);
    t[row][c4 * 4 + 0] = v[0]; t[row][c4 * 4 + 1] = v[1];
    t[row][c4 * 4 + 2] = v[2]; t[row][c4 * 4 + 3] = v[3];
  }
  __syncthreads();
#pragma unroll
  for (int p = 0; p < 4; ++p) {
    const int orow = p * 16 + sub;
    us4 o;
    o[0] = f2bfu(t[c4 * 4 + 0][orow]);
    o[1] = f2bfu(t[c4 * 4 + 1][orow]);
    o[2] = f2bfu(t[c4 * 4 + 2][orow]);
    o[3] = f2bfu(t[c4 * 4 + 3][orow]);
    *(us4*)(out + (size_t)(i0 + orow) * DIM + h0 + c4 * 4) = o;
  }
}

// ---------------- t1 = WqT·bk, t2 = WkT·bq (row-dots) ----------------
__global__ void t12_kernel(const unsigned short* __restrict__ WqT,
                           const unsigned short* __restrict__ WkT,
                           const float* __restrict__ bq, const float* __restrict__ bk,
                           float* __restrict__ t1, float* __restrict__ t2) {
  const int y = blockIdx.y;
  const unsigned short* Wt = y ? WkT : WqT;
  const float* vec = y ? bq : bk;
  float* tout = y ? t2 : t1;
  const int wave = threadIdx.x >> 6, lane = threadIdx.x & 63;
  const int i = blockIdx.x * 4 + wave;
  const us4* wr = (const us4*)(Wt + (size_t)i * DIM);
  float s = 0.f;
#pragma unroll
  for (int t = 0; t < 4; ++t) {
    us4 w4 = wr[lane + 64 * t];
    f32x4 b4 = *(const f32x4*)(vec + (lane + 64 * t) * 4);
    s += bfu2f(w4[0]) * b4[0] + bfu2f(w4[1]) * b4[1] +
         bfu2f(w4[2]) * b4[2] + bfu2f(w4[3]) * b4[3];
  }
#pragma unroll
  for (int o = 32; o; o >>= 1) s += __shfl_down(s, o);
  if (lane == 0) tout[i] = s;
}

// ---------------- path-pool weights w[b,j]; block 0 also: zbias=0, dval=bq·bk ----------
__global__ void pathw_kernel(const int* __restrict__ pos,
                             const float* __restrict__ bq, const float* __restrict__ bk,
                             float* __restrict__ w, float* __restrict__ zbias,
                             float* __restrict__ dval) {
  const int b = blockIdx.x;
  __shared__ int ps[SEQ];
  __shared__ int mcnt;
  __shared__ float dred[4];
  const int tid = threadIdx.x;
  if (tid == 0) mcnt = 0;
  __syncthreads();
  if (b == 0) {
    for (int i = tid; i < DIM; i += 256) zbias[i] = 0.f;
    float dp = 0.f;
    for (int i = tid; i < DIM; i += 256) dp += bq[i] * bk[i];
#pragma unroll
    for (int o = 32; o; o >>= 1) dp += __shfl_down(dp, o);
    if ((tid & 63) == 0) dred[tid >> 6] = dp;
  }
  for (int i = tid; i < SEQ; i += 256) ps[i] = pos[b * SEQ + i];
  __syncthreads();
  if (b == 0 && tid == 0) dval[0] = dred[0] + dred[1] + dred[2] + dred[3];
  int c = 0;
  for (int i = tid; i < SEQ; i += 256) c += ps[i];
  for (int o = 32; o; o >>= 1) c += __shfl_down(c, o);
  if ((tid & 63) == 0) atomicAdd(&mcnt, c);
  __syncthreads();
  const float invM = 1.0f / (float)mcnt;
  for (int j = tid; j < SEQ; j += 256) {
    float a = 0.f;
#pragma unroll
    for (int di = -1; di <= 1; ++di) {
      int i = j + di;
      if (i < 0 || i >= SEQ) continue;
      if (!ps[i]) continue;
      int s, e;
      if (i < 2) { s = 0; e = (i == 0) ? 2 : 3; }
      else { s = (ps[i - 2] == 1) ? i : (i - 1); e = i + 2; if (e > SEQ) e = SEQ; }
      if (s <= j && j < e) a += 1.0f / (float)(e - s);
    }
    w[b * SEQ + j] = a * invM;
  }
}

// ---------------- row-cast x -> bf16 with fused av/cv row-dots; also casts Wv ----------
__global__ void cast_row_kernel(const float* __restrict__ x, const float* __restrict__ Wv,
                                const float* __restrict__ t1, const float* __restrict__ t2,
                                const float* __restrict__ dval,
                                unsigned short* __restrict__ xb,
                                unsigned short* __restrict__ Wvb,
                                float* __restrict__ av, float* __restrict__ cvv) {
  const int blk = blockIdx.x;
  const int tid = threadIdx.x;
  if (blk >= BATCH * SEQ) {
    const int row = blk - BATCH * SEQ;
    const size_t base = (size_t)row * DIM + tid * 4;
    f32x4 v = *(const f32x4*)(Wv + base);
    us4 o;
    o[0] = f2bfu(v[0]); o[1] = f2bfu(v[1]); o[2] = f2bfu(v[2]); o[3] = f2bfu(v[3]);
    *(us4*)(Wvb + base) = o;
    return;
  }
  const size_t base = (size_t)blk * DIM + tid * 4;
  f32x4 v = *(const f32x4*)(x + base);
  us4 o;
  o[0] = f2bfu(v[0]); o[1] = f2bfu(v[1]); o[2] = f2bfu(v[2]); o[3] = f2bfu(v[3]);
  *(us4*)(xb + base) = o;
  const f32x4 q1 = *(const f32x4*)(t1 + tid * 4);
  const f32x4 q2 = *(const f32x4*)(t2 + tid * 4);
  float sa = v[0] * q1[0] + v[1] * q1[1] + v[2] * q1[2] + v[3] * q1[3];
  float sc = v[0] * q2[0] + v[1] * q2[1] + v[2] * q2[2] + v[3] * q2[3];
#pragma unroll
  for (int off = 32; off; off >>= 1) {
    sa += __shfl_down(sa, off);
    sc += __shfl_down(sc, off);
  }
  __shared__ float r1[4], r2[4];
  const int wave = tid >> 6, lane = tid & 63;
  if (lane == 0) { r1[wave] = sa; r2[wave] = sc; }
  __syncthreads();
  if (tid == 0) {
    const float scale = 0.03125f;
    av[blk]  = scale * (r1[0] + r1[1] + r1[2] + r1[3] + dval[0]);
    cvv[blk] = scale * (r2[0] + r2[1] + r2[2] + r2[3]);
  }
}

// ---------------- small bf16 NT GEMM (used for H only) ----------------
__global__ void proj_gemm(const unsigned short* __restrict__ A,
                          const unsigned short* __restrict__ W,
                          const float* __restrict__ bias, float alpha,
                          unsigned short* __restrict__ C, int M, int N, int K)
{
  __shared__ __align__(16) char smem[32768];
  float* Sl = (float*)smem;
  const int tid = threadIdx.x;
  const int wave = tid >> 6, lane = tid & 63;
  const int lr = lane & 15, lg = lane >> 4;
  const int wr = wave >> 1, wc = wave & 1;
  const int m0 = blockIdx.x * 128, n0 = blockIdx.y * 128;
  const int off0 = tid * 16, off1 = 4096 + tid * 16;
  const int r0 = off0 >> 6, ke0 = (off0 >> 1) & 31;
  const int r1 = off1 >> 6, ke1 = (off1 >> 1) & 31;
  f32x4 acc[4][4] = {};

  auto stage = [&](char* base, int kk) {
    async16(base + off0, A + (size_t)(m0 + r0) * K + kk + ke0);
    async16(base + off1, A + (size_t)(m0 + r1) * K + kk + ke1);
    async16(base + 8192 + off0, W + (size_t)(n0 + r0) * K + kk + ke0);
    async16(base + 8192 + off1, W + (size_t)(n0 + r1) * K + kk + ke1);
  };
  auto compute = [&](const char* base) {
    bf16x8 af[4], bfv[4];
#pragma unroll
    for (int i = 0; i < 4; ++i) {
      af[i]  = *(const bf16x8*)(base + ((wr * 64 + i * 16 + lr) << 6) + (lg << 4));
      bfv[i] = *(const bf16x8*)(base + 8192 + ((wc * 64 + i * 16 + lr) << 6) + (lg << 4));
    }
#pragma unroll
    for (int i = 0; i < 4; ++i)
#pragma unroll
      for (int j = 0; j < 4; ++j)
        acc[i][j] = __builtin_amdgcn_mfma_f32_16x16x32_bf16(af[i], bfv[j], acc[i][j], 0, 0, 0);
  };

  const int nt = K >> 5;
  stage(smem, 0);
  __syncthreads();
  int cur = 0;
  for (int k = 0; k < nt - 1; ++k) {
    stage(smem + ((cur ^ 1) << 14), (k + 1) << 5);
    compute(smem + (cur << 14));
    __syncthreads();
    cur ^= 1;
  }
  compute(smem + (cur << 14));
#pragma unroll
  for (int p = 0; p < 4; ++p) {
    __syncthreads();
    if (wr == (p >> 1)) {
      const int ibase = (p & 1) * 2;
#pragma unroll
      for (int ii = 0; ii < 2; ++ii) {
        const int i = ibase + ii;
#pragma unroll
        for (int j = 0; j < 4; ++j)
#pragma unroll
          for (int r = 0; r < 4; ++r)
            Sl[(ii * 16 + lg * 4 + r) * 132 + wc * 64 + j * 16 + lr] = acc[i][j][r];
      }
    }
    __syncthreads();
#pragma unroll
    for (int it = 0; it < 4; ++it) {
      const int v = tid + it * 256;
      const int lrow = v >> 5, c4 = v & 31;
      const int grow = m0 + p * 32 + lrow;
      const int col = n0 + c4 * 4;
      const f32x4 s4 = *(const f32x4*)(&Sl[lrow * 132 + c4 * 4]);
      const f32x4 b4 = *(const f32x4*)(bias + col);
      us4 o;
      o[0] = f2bfu((s4[0] + b4[0]) * alpha);
      o[1] = f2bfu((s4[1] + b4[1]) * alpha);
      o[2] = f2bfu((s4[2] + b4[2]) * alpha);
      o[3] = f2bfu((s4[3] + b4[3]) * alpha);
      *(us4*)(C + (size_t)grow * N + col) = o;
    }
  }
}

// ---------------- 256x256 deep-pipelined bf16 NT GEMM: C = bf16(A @ B^T) ----------------
// R18-verified structure (39.6 us) incl. T1 bijective XCD swizzle.
__global__ __launch_bounds__(512, 2)
void gemm256(const unsigned short* __restrict__ A,
             const unsigned short* __restrict__ B,
             unsigned short* __restrict__ C)
{
  extern __shared__ __align__(16) char smem[];   // 131072 B
  const int gx = gridDim.x, gy = gridDim.y;
  const int flat = blockIdx.x + gx * (blockIdx.y + gy * blockIdx.z);
  const int q8 = (gx * gy * gridDim.z) >> 3;
  const int tt = (flat & 7) * q8 + (flat >> 3);
  const int bz = tt / (gx * gy);
  const int rem = tt - bz * (gx * gy);
  const int m0 = (rem / gx) * 256;
  const int n0 = (rem % gx) * 256;
  const size_t boff = (size_t)bz << 20;
  const int tid = threadIdx.x;
  const int lane = tid & 63;
  const int wid = tid >> 6;
  const int wm = wid >> 2, wn = wid & 3;
  const int lr = lane & 15, lg = lane >> 4;
  const unsigned short* Ab = A + boff;
  const unsigned short* Bb = B + boff;

  int sr[2], se[2], sL[2];
#pragma unroll
  for (int l = 0; l < 2; ++l) {
    const int L = l * 8192 + tid * 16;
    const int r = L >> 6, sp = (L >> 4) & 3;
    sL[l] = L; sr[l] = r; se[l] = (sp ^ ((r >> 1) & 3)) * 8;
  }
  int aoff[8], boff_[4];
#pragma unroll
  for (int i = 0; i < 8; ++i) {
    const int row = wm * 128 + i * 16 + lr;
    aoff[i] = row * 64 + (lg ^ ((row >> 1) & 3)) * 16;
  }
#pragma unroll
  for (int j = 0; j < 4; ++j) {
    const int row = wn * 64 + j * 16 + lr;
    boff_[j] = row * 64 + (lg ^ ((row >> 1) & 3)) * 16;
  }

  auto stage = [&](int slot, int kt) {
    char* sa = smem + slot * 32768;
#pragma unroll
    for (int l = 0; l < 2; ++l)
      async16(sa + sL[l], Ab + (size_t)(m0 + sr[l]) * DIM + kt * 32 + se[l]);
    char* sb = sa + 16384;
#pragma unroll
    for (int l = 0; l < 2; ++l)
      async16(sb + sL[l], Bb + (size_t)(n0 + sr[l]) * DIM + kt * 32 + se[l]);
  };

  f32x4 acc[8][4] = {};
  stage(0, 0); stage(1, 1); stage(2, 2); stage(3, 3);

#pragma unroll
  for (int t = 0; t < 32; ++t) {
    if (t == 0)       asm volatile("s_waitcnt vmcnt(12)" ::: "memory");
    else if (t <= 29) asm volatile("s_waitcnt vmcnt(8)" ::: "memory");
    else if (t == 30) asm volatile("s_waitcnt vmcnt(4)" ::: "memory");
    else              asm volatile("s_waitcnt vmcnt(0)" ::: "memory");
    __builtin_amdgcn_s_barrier();
    const char* sa = smem + (t & 3) * 32768;
    const char* sb = sa + 16384;
    bf16x8 a[8], bfr[4];
#pragma unroll
    for (int i = 0; i < 8; ++i) a[i] = *(const bf16x8*)(sa + aoff[i]);
#pragma unroll
    for (int j = 0; j < 4; ++j) bfr[j] = *(const bf16x8*)(sb + boff_[j]);
    if (t >= 1 && t <= 28) stage((t + 3) & 3, t + 3);
    __builtin_amdgcn_s_setprio(1);
#pragma unroll
    for (int i = 0; i < 8; ++i)
#pragma unroll
      for (int j = 0; j < 4; ++j)
        acc[i][j] = __builtin_amdgcn_mfma_f32_16x16x32_bf16(a[i], bfr[j], acc[i][j], 0, 0, 0);
    __builtin_amdgcn_s_setprio(0);
  }

  unsigned short* Sl = (unsigned short*)smem;     // [128][260] bf16
  unsigned short* Cb = C + boff;
#pragma unroll
  for (int half = 0; half < 2; ++half) {
    __syncthreads();
    if (wm == half) {
#pragma unroll
      for (int i = 0; i < 8; ++i)
#pragma unroll
        for (int j = 0; j < 4; ++j)
#pragma unroll
          for (int r = 0; r < 4; ++r)
            Sl[(i * 16 + lg * 4 + r) * 260 + wn * 64 + j * 16 + lr] =
                f2bfu(acc[i][j][r]);
    }
    __syncthreads();
#pragma unroll
    for (int it = 0; it < 16; ++it) {
      const int v = tid + it * 512;
      const int row = v >> 6, c4 = v & 63;
      *(us4*)(Cb + (size_t)(m0 + half * 128 + row) * SEQ + n0 + c4 * 4) =
          *(const us4*)(&Sl[row * 260 + c4 * 4]);
    }
  }
}

// ---------------- fused exp + denom + u: 2 rows/wave, register accum ----------------
// XCD-affinity swizzle: XCD j handles batches {2j, 2j+1} — matching the S-gemm's
// placement, so the 2 MB/batch S tile is read back from the same L2 that wrote it.
__global__ void exp_fused_kernel(const unsigned short* __restrict__ S,
                                 const float* __restrict__ ag, const float* __restrict__ vg,
                                 const float* __restrict__ av, const float* __restrict__ cv,
                                 const float* __restrict__ w, float* __restrict__ part)
{
  __shared__ float red[4][SEQ];
  const int flat = blockIdx.x + 128 * blockIdx.y;   // 0..2047
  const int xcd = flat & 7;
  const int idx = flat >> 3;                        // 0..255
  const int b = xcd * 2 + (idx >> 7);               // batches {2j,2j+1} on XCD j
  const int bxs = idx & 127;                        // row-block within batch
  const int tid = threadIdx.x;
  const int wave = tid >> 6, lane = tid & 63;
  const float* agb = ag + ((size_t)b << 20);
  const float* vgb = vg + ((size_t)b << 20);
  const unsigned short* Sb = S + ((size_t)b << 20);
  const float* cvb = cv + b * SEQ;
  f32x4 cq[4];
#pragma unroll
  for (int qi = 0; qi < 4; ++qi)
    cq[qi] = *(const f32x4*)(cvb + (lane + 64 * qi) * 4);
  f32x4 ur[4] = {};
  const int r0 = bxs * 8 + wave * 2;
  const float w0 = w[b * SEQ + r0];
  const float w1 = w[b * SEQ + r0 + 1];
  us4 sv[2][4]; f32x4 a4[2][4], g4[2][4];
#pragma unroll
  for (int r = 0; r < 2; ++r) {
    const float wr_ = r ? w1 : w0;
    if (wr_ == 0.f) continue;
    const int row = r0 + r;
#pragma unroll
    for (int qi = 0; qi < 4; ++qi) {
      const size_t base = (size_t)row * SEQ + (lane + 64 * qi) * 4;
      sv[r][qi] = *(const us4*)(Sb + base);
      a4[r][qi] = *(const f32x4*)(agb + base);
      g4[r][qi] = *(const f32x4*)(vgb + base);
    }
  }
#pragma unroll
  for (int r = 0; r < 2; ++r) {
    const float wr_ = r ? w1 : w0;
    if (wr_ == 0.f) continue;
    const int row = r0 + r;
    const float arow = av[b * SEQ + row];
    float e[16];
    float rs = 0.f;
#pragma unroll
    for (int qi = 0; qi < 4; ++qi)
#pragma unroll
      for (int j = 0; j < 4; ++j) {
        const float ev = __expf(bfu2f(sv[r][qi][j]) + a4[r][qi][j] + g4[r][qi][j] +
                                arow + cq[qi][j]);
        e[qi * 4 + j] = ev;
        rs += ev;
      }
#pragma unroll
    for (int o2 = 32; o2; o2 >>= 1) rs += __shfl_xor(rs, o2);
    const float cn = wr_ / rs;
#pragma unroll
    for (int qi = 0; qi < 4; ++qi)
#pragma unroll
      for (int j = 0; j < 4; ++j)
        ur[qi][j] += cn * e[qi * 4 + j];
  }
#pragma unroll
  for (int qi = 0; qi < 4; ++qi)
    *(f32x4*)(&red[wave][(lane + 64 * qi) * 4]) = ur[qi];
  __syncthreads();
  const int col = tid * 4;
  f32x4 s0 = *(const f32x4*)(&red[0][col]);
  const f32x4 s1 = *(const f32x4*)(&red[1][col]);
  const f32x4 s2 = *(const f32x4*)(&red[2][col]);
  const f32x4 s3 = *(const f32x4*)(&red[3][col]);
  s0[0] += s1[0] + s2[0] + s3[0];
  s0[1] += s1[1] + s2[1] + s3[1];
  s0[2] += s1[2] + s2[2] + s3[2];
  s0[3] += s1[3] + s2[3] + s3[3];
  *(f32x4*)(part + ((size_t)(b * 128 + bxs) << 10) + col) = s0;
}

// ---------------- weighted column partial with inline u-reduction ----------------
__global__ void wcol_kernel(const unsigned short* __restrict__ Mt,
                            const float* __restrict__ wv,
                            const float* __restrict__ pin,
                            float* __restrict__ part) {
  const int nc = blockIdx.x;           // 16 chunks of 64 n
  const int b = blockIdx.y;
  const int tid = threadIdx.x;
  __shared__ float c[64];
  if (pin) {
    const int n = nc * 64 + (tid & 63);
    const int bl0 = (tid >> 6) * 32;
    float s = 0.f;
#pragma unroll 8
    for (int bl = 0; bl < 32; ++bl)
      s += pin[((size_t)(b * 128 + bl0 + bl) << 10) + n];
    __shared__ float cp[4][64];
    cp[tid >> 6][tid & 63] = s;
    __syncthreads();
    if (tid < 64) c[tid] = cp[0][tid] + cp[1][tid] + cp[2][tid] + cp[3][tid];
  } else {
    if (tid < 64) c[tid] = wv[b * SEQ + nc * 64 + tid];
  }
  __syncthreads();
  const unsigned short* p = Mt + ((size_t)b << 20) + ((size_t)(nc * 64) << 10) + tid * 4;
  f32x4 acc = {0.f, 0.f, 0.f, 0.f};
#pragma unroll 8
  for (int n = 0; n < 64; ++n) {
    const us4 v = *(const us4*)(p + ((size_t)n << 10));
    const float cn = c[n];
    acc[0] += cn * bfu2f(v[0]); acc[1] += cn * bfu2f(v[1]);
    acc[2] += cn * bfu2f(v[2]); acc[3] += cn * bfu2f(v[3]);
  }
  *(f32x4*)(part + (size_t)((b * 16 + nc) << 10) + tid * 4) = acc;
}

// ---------------- reduce part (nchunks per batch) -> vec[b][m] ----------------
__global__ void wred_kernel(const float* __restrict__ part, float* __restrict__ vec,
                            int nchunks) {
  const int b = blockIdx.x;
  const int tid = threadIdx.x;
  f32x4 s = {0.f, 0.f, 0.f, 0.f};
  for (int nc = 0; nc < nchunks; ++nc) {
    const f32x4 v = *(const f32x4*)(part + ((size_t)(b * nchunks + nc) << 10) + tid * 4);
    s[0] += v[0]; s[1] += v[1]; s[2] += v[2]; s[3] += v[3];
  }
  *(f32x4*)(vec + b * SEQ + tid * 4) = s;
}

// ---------------- item[b,h] = sum_d y[b,d]*Wv[h,d] + bv[h] ----------------
__global__ void item_kernel(const float* __restrict__ y,
                            const unsigned short* __restrict__ Wvb,
                            const float* __restrict__ bv, float* __restrict__ item) {
  const int b = blockIdx.x;
  const int hblk = blockIdx.y;
  __shared__ float ys[DIM];
  const int tid = threadIdx.x;
  for (int i = tid; i < DIM; i += 256) ys[i] = y[b * DIM + i];
  __syncthreads();
  const int wave = tid >> 6, lane = tid & 63;
  const int h = hblk * 4 + wave;
  const us4* wrow = (const us4*)(Wvb + (size_t)h * DIM);
  float acc = 0.f;
#pragma unroll
  for (int t = 0; t < 4; ++t) {
    us4 v = wrow[t * 64 + lane];
    const int d0 = (t * 64 + lane) * 4;
    acc += ys[d0] * bfu2f(v[0]) + ys[d0 + 1] * bfu2f(v[1]) +
           ys[d0 + 2] * bfu2f(v[2]) + ys[d0 + 3] * bfu2f(v[3]);
  }
  for (int o = 32; o; o >>= 1) acc += __shfl_down(acc, o);
  if (lane == 0) item[b * DIM + h] = acc + bv[h];
}

// ---------------- broadcast item[b,:] over n ----------------
__global__ void bcast_kernel(const float* __restrict__ item, float* __restrict__ out) {
  const int b = blockIdx.y;
  const int n = blockIdx.x;
  const f32x4* src = (const f32x4*)(item + b * DIM);
  f32x4* dst = (f32x4*)(out + (((size_t)b * SEQ + n) << 10));
  dst[threadIdx.x] = src[threadIdx.x];
}

extern "C" void kernel_launch(void* const* d_in, const int* in_sizes, int n_in,
                              void* d_out, int out_size, void* d_ws, size_t ws_size,
                              hipStream_t stream) {
  const float* x    = (const float*)d_in[0];
  const float* ag   = (const float*)d_in[1];
  const float* vgr  = (const float*)d_in[2];
  const float* Wq   = (const float*)d_in[3];
  const float* bq   = (const float*)d_in[4];
  const float* Wk   = (const float*)d_in[5];
  const float* bk   = (const float*)d_in[6];
  const float* Wv   = (const float*)d_in[7];
  const float* bv   = (const float*)d_in[8];
  const int*   pos  = (const int*)d_in[9];
  float* out = (float*)d_out;

  char* ws = (char*)d_ws;
  size_t off = 0;
  auto alloc = [&](size_t bytes) { void* p = ws + off; off += (bytes + 255) & ~(size_t)255; return p; };
  const size_t BNH = (size_t)BATCH * SEQ * DIM;
  unsigned short* xb   = (unsigned short*)alloc(BNH * 2);
  unsigned short* zb   = (unsigned short*)alloc(BNH * 2);
  unsigned short* S    = (unsigned short*)alloc(BNH * 2);
  unsigned short* WqT  = (unsigned short*)alloc((size_t)DIM * DIM * 2);
  unsigned short* WkT  = (unsigned short*)alloc((size_t)DIM * DIM * 2);
  unsigned short* Wvb  = (unsigned short*)alloc((size_t)DIM * DIM * 2);
  unsigned short* Hb   = (unsigned short*)alloc((size_t)DIM * DIM * 2);
  float* w     = (float*)alloc((size_t)BATCH * SEQ * 4);
  float* av    = (float*)alloc((size_t)BATCH * SEQ * 4);
  float* cvv   = (float*)alloc((size_t)BATCH * SEQ * 4);
  float* t1    = (float*)alloc((size_t)DIM * 4);
  float* t2    = (float*)alloc((size_t)DIM * 4);
  float* zbias = (float*)alloc((size_t)DIM * 4);
  float* dval  = (float*)alloc(256);
  float* y     = (float*)alloc((size_t)BATCH * DIM * 4);
  float* item  = (float*)alloc((size_t)BATCH * DIM * 4);
  float* partU = (float*)alloc((size_t)BATCH * 128 * SEQ * 4);  // 8 MB
  float* partY = (float*)alloc((size_t)BATCH * 16 * SEQ * 4);

  const float scale = 0.03125f;  // 1024^-0.5

  (void)hipFuncSetAttribute(reinterpret_cast<const void*>(gemm256),
                            hipFuncAttributeMaxDynamicSharedMemorySize, 131072);

  // weight transposes + bias-fold vectors + path weights
  castT_kernel<<<dim3(16, 16, 2), 256, 0, stream>>>(Wq, Wk, WqT, WkT);
  t12_kernel<<<dim3(256, 2), 256, 0, stream>>>(WqT, WkT, bq, bk, t1, t2);
  pathw_kernel<<<BATCH, 256, 0, stream>>>(pos, bq, bk, w, zbias, dval);

  // x cast + av/cv row-dots fused; Wv cast appended
  cast_row_kernel<<<BATCH * SEQ + DIM, 256, 0, stream>>>(x, Wv, t1, t2, dval,
                                                         xb, Wvb, av, cvv);

  // H = scale * (Wk^T Wq)
  proj_gemm<<<dim3(8, 8), 256, 0, stream>>>(WkT, WqT, zbias, scale, Hb, DIM, DIM, DIM);

  // z = x @ H^T   (256^2 deep-pipelined, XCD-swizzled)
  gemm256<<<dim3(4, 64, 1), 512, 131072, stream>>>(xb, Hb, zb);

  // S = z x^T (bf16, batched, XCD-swizzled: batches {2j,2j+1} on XCD j)
  gemm256<<<dim3(4, 4, BATCH), 512, 131072, stream>>>(zb, xb, S);

  // u-partials (XCD-affine with S producer)
  exp_fused_kernel<<<dim3(128, BATCH), 256, 0, stream>>>(S, ag, vgr, av, cvv, w, partU);

  // y-partials: partY = sum_m u[b,m] * x[b,m,d]  (u reduced inline from partU)
  wcol_kernel<<<dim3(16, BATCH), 256, 0, stream>>>(xb, nullptr, partU, partY);
  wred_kernel<<<BATCH, 256, 0, stream>>>(partY, y, 16);

  // item[b,h] = y@Wv^T + bv   (sum u == 1)
  item_kernel<<<dim3(BATCH, 256), 256, 0, stream>>>(y, Wvb, bv, item);

  // broadcast to [B,N,H]
  bcast_kernel<<<dim3(SEQ, BATCH), 256, 0, stream>>>(item, out);
}

// Round 22
// 191.967 us; speedup vs baseline: 1.0308x; 1.0308x over previous
//
#include <hip/hip_runtime.h>
#include <hip/hip_bf16.h>

#define BATCH 16
#define SEQ   1024
#define DIM   1024

typedef __attribute__((ext_vector_type(8))) short bf16x8;
typedef __attribute__((ext_vector_type(4))) float f32x4;
typedef __attribute__((ext_vector_type(4))) unsigned short us4;

__device__ __forceinline__ float bfu2f(unsigned short u) {
  union { unsigned int i; float f; } c; c.i = ((unsigned int)u) << 16; return c.f;
}
__device__ __forceinline__ unsigned short f2bfu(float f) {
  union { float f; unsigned int i; } c; c.f = f;
  return (unsigned short)((c.i + 0x7FFFu + ((c.i >> 16) & 1u)) >> 16);
}
__device__ __forceinline__ void async16(void* lds, const void* g) {
  __builtin_amdgcn_global_load_lds(
      (const __attribute__((address_space(1))) unsigned int*)g,
      (__attribute__((address_space(3))) unsigned int*)lds, 16, 0, 0);
}

// ---------------- transpose-cast: out[i,h] = bf16(in[h,i]) for Wq, Wk ----------------
__global__ void castT_kernel(const float* __restrict__ Wq, const float* __restrict__ Wk,
                             unsigned short* __restrict__ WqT,
                             unsigned short* __restrict__ WkT) {
  const float* in = (blockIdx.z == 0) ? Wq : Wk;
  unsigned short* out = (blockIdx.z == 0) ? WqT : WkT;
  __shared__ float t[64][65];
  const int h0 = blockIdx.x * 64, i0 = blockIdx.y * 64;
  const int tid = threadIdx.x;
  const int sub = tid >> 4, c4 = tid & 15;
#pragma unroll
  for (int p = 0; p < 4; ++p) {
    const int row = p * 16 + sub;
    f32x4 v = *(const f32x4*)(in + (size_t)(h0 + row) * DIM + i0 + c4 * 4);
    t[row][c4 * 4 + 0] = v[0]; t[row][c4 * 4 + 1] = v[1];
    t[row][c4 * 4 + 2] = v[2]; t[row][c4 * 4 + 3] = v[3];
  }
  __syncthreads();
#pragma unroll
  for (int p = 0; p < 4; ++p) {
    const int orow = p * 16 + sub;
    us4 o;
    o[0] = f2bfu(t[c4 * 4 + 0][orow]);
    o[1] = f2bfu(t[c4 * 4 + 1][orow]);
    o[2] = f2bfu(t[c4 * 4 + 2][orow]);
    o[3] = f2bfu(t[c4 * 4 + 3][orow]);
    *(us4*)(out + (size_t)(i0 + orow) * DIM + h0 + c4 * 4) = o;
  }
}

// ---------------- t1 = WqT·bk, t2 = WkT·bq (row-dots) ----------------
__global__ void t12_kernel(const unsigned short* __restrict__ WqT,
                           const unsigned short* __restrict__ WkT,
                           const float* __restrict__ bq, const float* __restrict__ bk,
                           float* __restrict__ t1, float* __restrict__ t2) {
  const int y = blockIdx.y;
  const unsigned short* Wt = y ? WkT : WqT;
  const float* vec = y ? bq : bk;
  float* tout = y ? t2 : t1;
  const int wave = threadIdx.x >> 6, lane = threadIdx.x & 63;
  const int i = blockIdx.x * 4 + wave;
  const us4* wr = (const us4*)(Wt + (size_t)i * DIM);
  float s = 0.f;
#pragma unroll
  for (int t = 0; t < 4; ++t) {
    us4 w4 = wr[lane + 64 * t];
    f32x4 b4 = *(const f32x4*)(vec + (lane + 64 * t) * 4);
    s += bfu2f(w4[0]) * b4[0] + bfu2f(w4[1]) * b4[1] +
         bfu2f(w4[2]) * b4[2] + bfu2f(w4[3]) * b4[3];
  }
#pragma unroll
  for (int o = 32; o; o >>= 1) s += __shfl_down(s, o);
  if (lane == 0) tout[i] = s;
}

// ---------------- path-pool weights w[b,j]; block 0 also: zbias=0, dval=bq·bk ----------
__global__ void pathw_kernel(const int* __restrict__ pos,
                             const float* __restrict__ bq, const float* __restrict__ bk,
                             float* __restrict__ w, float* __restrict__ zbias,
                             float* __restrict__ dval) {
  const int b = blockIdx.x;
  __shared__ int ps[SEQ];
  __shared__ int mcnt;
  __shared__ float dred[4];
  const int tid = threadIdx.x;
  if (tid == 0) mcnt = 0;
  __syncthreads();
  if (b == 0) {
    for (int i = tid; i < DIM; i += 256) zbias[i] = 0.f;
    float dp = 0.f;
    for (int i = tid; i < DIM; i += 256) dp += bq[i] * bk[i];
#pragma unroll
    for (int o = 32; o; o >>= 1) dp += __shfl_down(dp, o);
    if ((tid & 63) == 0) dred[tid >> 6] = dp;
  }
  for (int i = tid; i < SEQ; i += 256) ps[i] = pos[b * SEQ + i];
  __syncthreads();
  if (b == 0 && tid == 0) dval[0] = dred[0] + dred[1] + dred[2] + dred[3];
  int c = 0;
  for (int i = tid; i < SEQ; i += 256) c += ps[i];
  for (int o = 32; o; o >>= 1) c += __shfl_down(c, o);
  if ((tid & 63) == 0) atomicAdd(&mcnt, c);
  __syncthreads();
  const float invM = 1.0f / (float)mcnt;
  for (int j = tid; j < SEQ; j += 256) {
    float a = 0.f;
#pragma unroll
    for (int di = -1; di <= 1; ++di) {
      int i = j + di;
      if (i < 0 || i >= SEQ) continue;
      if (!ps[i]) continue;
      int s, e;
      if (i < 2) { s = 0; e = (i == 0) ? 2 : 3; }
      else { s = (ps[i - 2] == 1) ? i : (i - 1); e = i + 2; if (e > SEQ) e = SEQ; }
      if (s <= j && j < e) a += 1.0f / (float)(e - s);
    }
    w[b * SEQ + j] = a * invM;
  }
}

// ---------------- row-cast x -> bf16 with fused av/cv row-dots; also casts Wv ----------
__global__ void cast_row_kernel(const float* __restrict__ x, const float* __restrict__ Wv,
                                const float* __restrict__ t1, const float* __restrict__ t2,
                                const float* __restrict__ dval,
                                unsigned short* __restrict__ xb,
                                unsigned short* __restrict__ Wvb,
                                float* __restrict__ av, float* __restrict__ cvv) {
  const int blk = blockIdx.x;
  const int tid = threadIdx.x;
  if (blk >= BATCH * SEQ) {
    const int row = blk - BATCH * SEQ;
    const size_t base = (size_t)row * DIM + tid * 4;
    f32x4 v = *(const f32x4*)(Wv + base);
    us4 o;
    o[0] = f2bfu(v[0]); o[1] = f2bfu(v[1]); o[2] = f2bfu(v[2]); o[3] = f2bfu(v[3]);
    *(us4*)(Wvb + base) = o;
    return;
  }
  const size_t base = (size_t)blk * DIM + tid * 4;
  f32x4 v = *(const f32x4*)(x + base);
  us4 o;
  o[0] = f2bfu(v[0]); o[1] = f2bfu(v[1]); o[2] = f2bfu(v[2]); o[3] = f2bfu(v[3]);
  *(us4*)(xb + base) = o;
  const f32x4 q1 = *(const f32x4*)(t1 + tid * 4);
  const f32x4 q2 = *(const f32x4*)(t2 + tid * 4);
  float sa = v[0] * q1[0] + v[1] * q1[1] + v[2] * q1[2] + v[3] * q1[3];
  float sc = v[0] * q2[0] + v[1] * q2[1] + v[2] * q2[2] + v[3] * q2[3];
#pragma unroll
  for (int off = 32; off; off >>= 1) {
    sa += __shfl_down(sa, off);
    sc += __shfl_down(sc, off);
  }
  __shared__ float r1[4], r2[4];
  const int wave = tid >> 6, lane = tid & 63;
  if (lane == 0) { r1[wave] = sa; r2[wave] = sc; }
  __syncthreads();
  if (tid == 0) {
    const float scale = 0.03125f;
    av[blk]  = scale * (r1[0] + r1[1] + r1[2] + r1[3] + dval[0]);
    cvv[blk] = scale * (r2[0] + r2[1] + r2[2] + r2[3]);
  }
}

// ---------------- small bf16 NT GEMM (used for H only) ----------------
__global__ void proj_gemm(const unsigned short* __restrict__ A,
                          const unsigned short* __restrict__ W,
                          const float* __restrict__ bias, float alpha,
                          unsigned short* __restrict__ C, int M, int N, int K)
{
  __shared__ __align__(16) char smem[32768];
  float* Sl = (float*)smem;
  const int tid = threadIdx.x;
  const int wave = tid >> 6, lane = tid & 63;
  const int lr = lane & 15, lg = lane >> 4;
  const int wr = wave >> 1, wc = wave & 1;
  const int m0 = blockIdx.x * 128, n0 = blockIdx.y * 128;
  const int off0 = tid * 16, off1 = 4096 + tid * 16;
  const int r0 = off0 >> 6, ke0 = (off0 >> 1) & 31;
  const int r1 = off1 >> 6, ke1 = (off1 >> 1) & 31;
  f32x4 acc[4][4] = {};

  auto stage = [&](char* base, int kk) {
    async16(base + off0, A + (size_t)(m0 + r0) * K + kk + ke0);
    async16(base + off1, A + (size_t)(m0 + r1) * K + kk + ke1);
    async16(base + 8192 + off0, W + (size_t)(n0 + r0) * K + kk + ke0);
    async16(base + 8192 + off1, W + (size_t)(n0 + r1) * K + kk + ke1);
  };
  auto compute = [&](const char* base) {
    bf16x8 af[4], bfv[4];
#pragma unroll
    for (int i = 0; i < 4; ++i) {
      af[i]  = *(const bf16x8*)(base + ((wr * 64 + i * 16 + lr) << 6) + (lg << 4));
      bfv[i] = *(const bf16x8*)(base + 8192 + ((wc * 64 + i * 16 + lr) << 6) + (lg << 4));
    }
#pragma unroll
    for (int i = 0; i < 4; ++i)
#pragma unroll
      for (int j = 0; j < 4; ++j)
        acc[i][j] = __builtin_amdgcn_mfma_f32_16x16x32_bf16(af[i], bfv[j], acc[i][j], 0, 0, 0);
  };

  const int nt = K >> 5;
  stage(smem, 0);
  __syncthreads();
  int cur = 0;
  for (int k = 0; k < nt - 1; ++k) {
    stage(smem + ((cur ^ 1) << 14), (k + 1) << 5);
    compute(smem + (cur << 14));
    __syncthreads();
    cur ^= 1;
  }
  compute(smem + (cur << 14));
#pragma unroll
  for (int p = 0; p < 4; ++p) {
    __syncthreads();
    if (wr == (p >> 1)) {
      const int ibase = (p & 1) * 2;
#pragma unroll
      for (int ii = 0; ii < 2; ++ii) {
        const int i = ibase + ii;
#pragma unroll
        for (int j = 0; j < 4; ++j)
#pragma unroll
          for (int r = 0; r < 4; ++r)
            Sl[(ii * 16 + lg * 4 + r) * 132 + wc * 64 + j * 16 + lr] = acc[i][j][r];
      }
    }
    __syncthreads();
#pragma unroll
    for (int it = 0; it < 4; ++it) {
      const int v = tid + it * 256;
      const int lrow = v >> 5, c4 = v & 31;
      const int grow = m0 + p * 32 + lrow;
      const int col = n0 + c4 * 4;
      const f32x4 s4 = *(const f32x4*)(&Sl[lrow * 132 + c4 * 4]);
      const f32x4 b4 = *(const f32x4*)(bias + col);
      us4 o;
      o[0] = f2bfu((s4[0] + b4[0]) * alpha);
      o[1] = f2bfu((s4[1] + b4[1]) * alpha);
      o[2] = f2bfu((s4[2] + b4[2]) * alpha);
      o[3] = f2bfu((s4[3] + b4[3]) * alpha);
      *(us4*)(C + (size_t)grow * N + col) = o;
    }
  }
}

// ---------------- 256x256 deep-pipelined bf16 NT GEMM: C = bf16(A @ B^T) ----------------
// R18-verified structure (39.6 us) incl. T1 bijective XCD swizzle.
__global__ __launch_bounds__(512, 2)
void gemm256(const unsigned short* __restrict__ A,
             const unsigned short* __restrict__ B,
             unsigned short* __restrict__ C)
{
  extern __shared__ __align__(16) char smem[];   // 131072 B
  const int gx = gridDim.x, gy = gridDim.y;
  const int flat = blockIdx.x + gx * (blockIdx.y + gy * blockIdx.z);
  const int q8 = (gx * gy * gridDim.z) >> 3;
  const int tt = (flat & 7) * q8 + (flat >> 3);
  const int bz = tt / (gx * gy);
  const int rem = tt - bz * (gx * gy);
  const int m0 = (rem / gx) * 256;
  const int n0 = (rem % gx) * 256;
  const size_t boff = (size_t)bz << 20;
  const int tid = threadIdx.x;
  const int lane = tid & 63;
  const int wid = tid >> 6;
  const int wm = wid >> 2, wn = wid & 3;
  const int lr = lane & 15, lg = lane >> 4;
  const unsigned short* Ab = A + boff;
  const unsigned short* Bb = B + boff;

  int sr[2], se[2], sL[2];
#pragma unroll
  for (int l = 0; l < 2; ++l) {
    const int L = l * 8192 + tid * 16;
    const int r = L >> 6, sp = (L >> 4) & 3;
    sL[l] = L; sr[l] = r; se[l] = (sp ^ ((r >> 1) & 3)) * 8;
  }
  int aoff[8], boff_[4];
#pragma unroll
  for (int i = 0; i < 8; ++i) {
    const int row = wm * 128 + i * 16 + lr;
    aoff[i] = row * 64 + (lg ^ ((row >> 1) & 3)) * 16;
  }
#pragma unroll
  for (int j = 0; j < 4; ++j) {
    const int row = wn * 64 + j * 16 + lr;
    boff_[j] = row * 64 + (lg ^ ((row >> 1) & 3)) * 16;
  }

  auto stage = [&](int slot, int kt) {
    char* sa = smem + slot * 32768;
#pragma unroll
    for (int l = 0; l < 2; ++l)
      async16(sa + sL[l], Ab + (size_t)(m0 + sr[l]) * DIM + kt * 32 + se[l]);
    char* sb = sa + 16384;
#pragma unroll
    for (int l = 0; l < 2; ++l)
      async16(sb + sL[l], Bb + (size_t)(n0 + sr[l]) * DIM + kt * 32 + se[l]);
  };

  f32x4 acc[8][4] = {};
  stage(0, 0); stage(1, 1); stage(2, 2); stage(3, 3);

#pragma unroll
  for (int t = 0; t < 32; ++t) {
    if (t == 0)       asm volatile("s_waitcnt vmcnt(12)" ::: "memory");
    else if (t <= 29) asm volatile("s_waitcnt vmcnt(8)" ::: "memory");
    else if (t == 30) asm volatile("s_waitcnt vmcnt(4)" ::: "memory");
    else              asm volatile("s_waitcnt vmcnt(0)" ::: "memory");
    __builtin_amdgcn_s_barrier();
    const char* sa = smem + (t & 3) * 32768;
    const char* sb = sa + 16384;
    bf16x8 a[8], bfr[4];
#pragma unroll
    for (int i = 0; i < 8; ++i) a[i] = *(const bf16x8*)(sa + aoff[i]);
#pragma unroll
    for (int j = 0; j < 4; ++j) bfr[j] = *(const bf16x8*)(sb + boff_[j]);
    if (t >= 1 && t <= 28) stage((t + 3) & 3, t + 3);
    __builtin_amdgcn_s_setprio(1);
#pragma unroll
    for (int i = 0; i < 8; ++i)
#pragma unroll
      for (int j = 0; j < 4; ++j)
        acc[i][j] = __builtin_amdgcn_mfma_f32_16x16x32_bf16(a[i], bfr[j], acc[i][j], 0, 0, 0);
    __builtin_amdgcn_s_setprio(0);
  }

  unsigned short* Sl = (unsigned short*)smem;     // [128][260] bf16
  unsigned short* Cb = C + boff;
#pragma unroll
  for (int half = 0; half < 2; ++half) {
    __syncthreads();
    if (wm == half) {
#pragma unroll
      for (int i = 0; i < 8; ++i)
#pragma unroll
        for (int j = 0; j < 4; ++j)
#pragma unroll
          for (int r = 0; r < 4; ++r)
            Sl[(i * 16 + lg * 4 + r) * 260 + wn * 64 + j * 16 + lr] =
                f2bfu(acc[i][j][r]);
    }
    __syncthreads();
#pragma unroll
    for (int it = 0; it < 16; ++it) {
      const int v = tid + it * 512;
      const int row = v >> 6, c4 = v & 63;
      *(us4*)(Cb + (size_t)(m0 + half * 128 + row) * SEQ + n0 + c4 * 4) =
          *(const us4*)(&Sl[row * 260 + c4 * 4]);
    }
  }
}

// ---------------- fused exp + denom + u: 2 rows/wave, register accum (R20 form) ----------
__global__ void exp_fused_kernel(const unsigned short* __restrict__ S,
                                 const float* __restrict__ ag, const float* __restrict__ vg,
                                 const float* __restrict__ av, const float* __restrict__ cv,
                                 const float* __restrict__ w, float* __restrict__ part)
{
  __shared__ float red[4][SEQ];
  const int b = blockIdx.y;
  const int tid = threadIdx.x;
  const int wave = tid >> 6, lane = tid & 63;
  const float* agb = ag + ((size_t)b << 20);
  const float* vgb = vg + ((size_t)b << 20);
  const unsigned short* Sb = S + ((size_t)b << 20);
  const float* cvb = cv + b * SEQ;
  f32x4 cq[4];
#pragma unroll
  for (int qi = 0; qi < 4; ++qi)
    cq[qi] = *(const f32x4*)(cvb + (lane + 64 * qi) * 4);
  f32x4 ur[4] = {};
  const int r0 = blockIdx.x * 8 + wave * 2;
  const float w0 = w[b * SEQ + r0];
  const float w1 = w[b * SEQ + r0 + 1];
  us4 sv[2][4]; f32x4 a4[2][4], g4[2][4];
#pragma unroll
  for (int r = 0; r < 2; ++r) {
    const float wr_ = r ? w1 : w0;
    if (wr_ == 0.f) continue;
    const int row = r0 + r;
#pragma unroll
    for (int qi = 0; qi < 4; ++qi) {
      const size_t base = (size_t)row * SEQ + (lane + 64 * qi) * 4;
      sv[r][qi] = *(const us4*)(Sb + base);
      a4[r][qi] = *(const f32x4*)(agb + base);
      g4[r][qi] = *(const f32x4*)(vgb + base);
    }
  }
#pragma unroll
  for (int r = 0; r < 2; ++r) {
    const float wr_ = r ? w1 : w0;
    if (wr_ == 0.f) continue;
    const int row = r0 + r;
    const float arow = av[b * SEQ + row];
    float e[16];
    float rs = 0.f;
#pragma unroll
    for (int qi = 0; qi < 4; ++qi)
#pragma unroll
      for (int j = 0; j < 4; ++j) {
        const float ev = __expf(bfu2f(sv[r][qi][j]) + a4[r][qi][j] + g4[r][qi][j] +
                                arow + cq[qi][j]);
        e[qi * 4 + j] = ev;
        rs += ev;
      }
#pragma unroll
    for (int o2 = 32; o2; o2 >>= 1) rs += __shfl_xor(rs, o2);
    const float cn = wr_ / rs;
#pragma unroll
    for (int qi = 0; qi < 4; ++qi)
#pragma unroll
      for (int j = 0; j < 4; ++j)
        ur[qi][j] += cn * e[qi * 4 + j];
  }
#pragma unroll
  for (int qi = 0; qi < 4; ++qi)
    *(f32x4*)(&red[wave][(lane + 64 * qi) * 4]) = ur[qi];
  __syncthreads();
  const int col = tid * 4;
  f32x4 s0 = *(const f32x4*)(&red[0][col]);
  const f32x4 s1 = *(const f32x4*)(&red[1][col]);
  const f32x4 s2 = *(const f32x4*)(&red[2][col]);
  const f32x4 s3 = *(const f32x4*)(&red[3][col]);
  s0[0] += s1[0] + s2[0] + s3[0];
  s0[1] += s1[1] + s2[1] + s3[1];
  s0[2] += s1[2] + s2[2] + s3[2];
  s0[3] += s1[3] + s2[3] + s3[3];
  *(f32x4*)(part + ((size_t)(b * 128 + blockIdx.x) << 10) + col) = s0;
}

// ---------------- weighted column partial with inline u-reduction ----------------
__global__ void wcol_kernel(const unsigned short* __restrict__ Mt,
                            const float* __restrict__ wv,
                            const float* __restrict__ pin,
                            float* __restrict__ part) {
  const int nc = blockIdx.x;           // 16 chunks of 64 n
  const int b = blockIdx.y;
  const int tid = threadIdx.x;
  __shared__ float c[64];
  if (pin) {
    const int n = nc * 64 + (tid & 63);
    const int bl0 = (tid >> 6) * 32;
    float s = 0.f;
#pragma unroll 8
    for (int bl = 0; bl < 32; ++bl)
      s += pin[((size_t)(b * 128 + bl0 + bl) << 10) + n];
    __shared__ float cp[4][64];
    cp[tid >> 6][tid & 63] = s;
    __syncthreads();
    if (tid < 64) c[tid] = cp[0][tid] + cp[1][tid] + cp[2][tid] + cp[3][tid];
  } else {
    if (tid < 64) c[tid] = wv[b * SEQ + nc * 64 + tid];
  }
  __syncthreads();
  const unsigned short* p = Mt + ((size_t)b << 20) + ((size_t)(nc * 64) << 10) + tid * 4;
  f32x4 acc = {0.f, 0.f, 0.f, 0.f};
#pragma unroll 8
  for (int n = 0; n < 64; ++n) {
    const us4 v = *(const us4*)(p + ((size_t)n << 10));
    const float cn = c[n];
    acc[0] += cn * bfu2f(v[0]); acc[1] += cn * bfu2f(v[1]);
    acc[2] += cn * bfu2f(v[2]); acc[3] += cn * bfu2f(v[3]);
  }
  *(f32x4*)(part + (size_t)((b * 16 + nc) << 10) + tid * 4) = acc;
}

// ---------------- reduce part (nchunks per batch) -> vec[b][m] ----------------
__global__ void wred_kernel(const float* __restrict__ part, float* __restrict__ vec,
                            int nchunks) {
  const int b = blockIdx.x;
  const int tid = threadIdx.x;
  f32x4 s = {0.f, 0.f, 0.f, 0.f};
  for (int nc = 0; nc < nchunks; ++nc) {
    const f32x4 v = *(const f32x4*)(part + ((size_t)(b * nchunks + nc) << 10) + tid * 4);
    s[0] += v[0]; s[1] += v[1]; s[2] += v[2]; s[3] += v[3];
  }
  *(f32x4*)(vec + b * SEQ + tid * 4) = s;
}

// ---------------- item[b,h] = sum_d y[b,d]*Wv[h,d] + bv[h] ----------------
__global__ void item_kernel(const float* __restrict__ y,
                            const unsigned short* __restrict__ Wvb,
                            const float* __restrict__ bv, float* __restrict__ item) {
  const int b = blockIdx.x;
  const int hblk = blockIdx.y;
  __shared__ float ys[DIM];
  const int tid = threadIdx.x;
  for (int i = tid; i < DIM; i += 256) ys[i] = y[b * DIM + i];
  __syncthreads();
  const int wave = tid >> 6, lane = tid & 63;
  const int h = hblk * 4 + wave;
  const us4* wrow = (const us4*)(Wvb + (size_t)h * DIM);
  float acc = 0.f;
#pragma unroll
  for (int t = 0; t < 4; ++t) {
    us4 v = wrow[t * 64 + lane];
    const int d0 = (t * 64 + lane) * 4;
    acc += ys[d0] * bfu2f(v[0]) + ys[d0 + 1] * bfu2f(v[1]) +
           ys[d0 + 2] * bfu2f(v[2]) + ys[d0 + 3] * bfu2f(v[3]);
  }
  for (int o = 32; o; o >>= 1) acc += __shfl_down(acc, o);
  if (lane == 0) item[b * DIM + h] = acc + bv[h];
}

// ---------------- broadcast item[b,:] over n ----------------
__global__ void bcast_kernel(const float* __restrict__ item, float* __restrict__ out) {
  const int b = blockIdx.y;
  const int n = blockIdx.x;
  const f32x4* src = (const f32x4*)(item + b * DIM);
  f32x4* dst = (f32x4*)(out + (((size_t)b * SEQ + n) << 10));
  dst[threadIdx.x] = src[threadIdx.x];
}

extern "C" void kernel_launch(void* const* d_in, const int* in_sizes, int n_in,
                              void* d_out, int out_size, void* d_ws, size_t ws_size,
                              hipStream_t stream) {
  const float* x    = (const float*)d_in[0];
  const float* ag   = (const float*)d_in[1];
  const float* vgr  = (const float*)d_in[2];
  const float* Wq   = (const float*)d_in[3];
  const float* bq   = (const float*)d_in[4];
  const float* Wk   = (const float*)d_in[5];
  const float* bk   = (const float*)d_in[6];
  const float* Wv   = (const float*)d_in[7];
  const float* bv   = (const float*)d_in[8];
  const int*   pos  = (const int*)d_in[9];
  float* out = (float*)d_out;

  char* ws = (char*)d_ws;
  size_t off = 0;
  auto alloc = [&](size_t bytes) { void* p = ws + off; off += (bytes + 255) & ~(size_t)255; return p; };
  const size_t BNH = (size_t)BATCH * SEQ * DIM;
  unsigned short* xb   = (unsigned short*)alloc(BNH * 2);
  unsigned short* zb   = (unsigned short*)alloc(BNH * 2);
  unsigned short* S    = (unsigned short*)alloc(BNH * 2);
  unsigned short* WqT  = (unsigned short*)alloc((size_t)DIM * DIM * 2);
  unsigned short* WkT  = (unsigned short*)alloc((size_t)DIM * DIM * 2);
  unsigned short* Wvb  = (unsigned short*)alloc((size_t)DIM * DIM * 2);
  unsigned short* Hb   = (unsigned short*)alloc((size_t)DIM * DIM * 2);
  float* w     = (float*)alloc((size_t)BATCH * SEQ * 4);
  float* av    = (float*)alloc((size_t)BATCH * SEQ * 4);
  float* cvv   = (float*)alloc((size_t)BATCH * SEQ * 4);
  float* t1    = (float*)alloc((size_t)DIM * 4);
  float* t2    = (float*)alloc((size_t)DIM * 4);
  float* zbias = (float*)alloc((size_t)DIM * 4);
  float* dval  = (float*)alloc(256);
  float* y     = (float*)alloc((size_t)BATCH * DIM * 4);
  float* item  = (float*)alloc((size_t)BATCH * DIM * 4);
  float* partU = (float*)alloc((size_t)BATCH * 128 * SEQ * 4);  // 8 MB
  float* partY = (float*)alloc((size_t)BATCH * 16 * SEQ * 4);

  const float scale = 0.03125f;  // 1024^-0.5

  (void)hipFuncSetAttribute(reinterpret_cast<const void*>(gemm256),
                            hipFuncAttributeMaxDynamicSharedMemorySize, 131072);

  // weight transposes + bias-fold vectors + path weights
  castT_kernel<<<dim3(16, 16, 2), 256, 0, stream>>>(Wq, Wk, WqT, WkT);
  t12_kernel<<<dim3(256, 2), 256, 0, stream>>>(WqT, WkT, bq, bk, t1, t2);
  pathw_kernel<<<BATCH, 256, 0, stream>>>(pos, bq, bk, w, zbias, dval);

  // x cast + av/cv row-dots fused; Wv cast appended
  cast_row_kernel<<<BATCH * SEQ + DIM, 256, 0, stream>>>(x, Wv, t1, t2, dval,
                                                         xb, Wvb, av, cvv);

  // H = scale * (Wk^T Wq)
  proj_gemm<<<dim3(8, 8), 256, 0, stream>>>(WkT, WqT, zbias, scale, Hb, DIM, DIM, DIM);

  // z = x @ H^T   (256^2 deep-pipelined, XCD-swizzled)
  gemm256<<<dim3(4, 64, 1), 512, 131072, stream>>>(xb, Hb, zb);

  // S = z x^T (bf16, batched, XCD-swizzled)
  gemm256<<<dim3(4, 4, BATCH), 512, 131072, stream>>>(zb, xb, S);

  // u-partials: partU[b][blk][m] = sum_{rows in blk} (w/denom) * exp(S+a+c+G)
  exp_fused_kernel<<<dim3(128, BATCH), 256, 0, stream>>>(S, ag, vgr, av, cvv, w, partU);

  // y-partials: partY = sum_m u[b,m] * x[b,m,d]  (u reduced inline from partU)
  wcol_kernel<<<dim3(16, BATCH), 256, 0, stream>>>(xb, nullptr, partU, partY);
  wred_kernel<<<BATCH, 256, 0, stream>>>(partY, y, 16);

  // item[b,h] = y@Wv^T + bv   (sum u == 1)
  item_kernel<<<dim3(BATCH, 256), 256, 0, stream>>>(y, Wvb, bv, item);

  // broadcast to [B,N,H]
  bcast_kernel<<<dim3(SEQ, BATCH), 256, 0, stream>>>(item, out);
}